// Round 1
// baseline (452.207 us; speedup 1.0000x reference)
//
#include <hip/hip_runtime.h>
#include <stdint.h>

// QJL estimator: est[row] = DEQ * sum_m sign(key_row . S_m) * (query_row . S_m)
// Strategy:
//   kernel qjl_prep : split S (fp32) into Sh + Sl bf16 pair (exact-ish 16-bit split), zero worklist counter
//   kernel qjl_main : per-wave 16 rows x 256 m, 16x16x32 bf16 MFMA.
//                     kproj = kh*Sh + kl*Sh + kh*Sl   (error ~3e-5 rms)
//                     qproj = qh*Sh                   (est noise ~0.003, threshold 0.118)
//                     |kproj| < DELTA  -> push (row,m,sign_lp) to worklist
//   kernel qjl_fix  : fp64 recompute of borderline dots, atomic correction of out[row]
//
// Layout assumptions (gfx950 mfma_f32_16x16x32_bf16, per learn_hip m89-verified):
//   A-frag: lane l holds A[m = l&15, k = (l>>4)*8 + j], j=0..7 contiguous
//   B-frag: lane l holds B[k = (l>>4)*8 + j, n = l&15]  (= S[n_m, k] for B^T layout)
//   C/D  : col(N) = lane&15, row(M) = (lane>>4)*4 + reg

typedef __attribute__((ext_vector_type(8))) short bf16x8;
typedef __attribute__((ext_vector_type(4))) float f32x4;

#define DEQUANT 0.004895758348888673f  // sqrt(pi/2)/256
#define DELTA 0.01f

static __device__ __forceinline__ unsigned short f2bf(float f) {
  union { float f; uint32_t u; } v; v.f = f;
  return (unsigned short)((v.u + 0x7FFFu + ((v.u >> 16) & 1u)) >> 16);  // RNE
}
static __device__ __forceinline__ float bf2f(unsigned short h) {
  union { uint32_t u; float f; } v; v.u = ((uint32_t)h) << 16;
  return v.f;
}

__global__ void qjl_prep(const float* __restrict__ S, unsigned short* __restrict__ Sh,
                         unsigned short* __restrict__ Sl, unsigned int* __restrict__ wl_count,
                         int n) {
  int i = blockIdx.x * blockDim.x + threadIdx.x;
  if (i == 0) *wl_count = 0u;  // ws is re-poisoned 0xAA before every call
  if (i < n) {
    float s = S[i];
    unsigned short h = f2bf(s);
    Sh[i] = h;
    Sl[i] = f2bf(s - bf2f(h));
  }
}

__global__ __launch_bounds__(256) void qjl_main(
    const float* __restrict__ Q, const float* __restrict__ K,
    const unsigned short* __restrict__ Sh, const unsigned short* __restrict__ Sl,
    float* __restrict__ out, unsigned int* __restrict__ wl_count,
    unsigned int* __restrict__ wl, unsigned int wl_cap) {
  const int wave = threadIdx.x >> 6;
  const int lane = threadIdx.x & 63;
  const int col  = lane & 15;   // A row-index / B,C col-index within tile
  const int kg   = lane >> 4;   // k-group
  const int rowbase = (blockIdx.x * 4 + wave) * 16;

  f32x4 accq[16], acck[16];
#pragma unroll
  for (int f = 0; f < 16; ++f) {
    accq[f] = (f32x4){0.f, 0.f, 0.f, 0.f};
    acck[f] = (f32x4){0.f, 0.f, 0.f, 0.f};
  }

  const float* qrow = Q + (size_t)(rowbase + col) * 128;
  const float* krow = K + (size_t)(rowbase + col) * 128;

#pragma unroll
  for (int ks = 0; ks < 4; ++ks) {
    const int off = ks * 32 + kg * 8;
    float qf[8], kf[8];
    *(float4*)(&qf[0]) = *(const float4*)(qrow + off);
    *(float4*)(&qf[4]) = *(const float4*)(qrow + off + 4);
    *(float4*)(&kf[0]) = *(const float4*)(krow + off);
    *(float4*)(&kf[4]) = *(const float4*)(krow + off + 4);
    bf16x8 qa, kha, kla;
#pragma unroll
    for (int j = 0; j < 8; ++j) {
      qa[j] = (short)f2bf(qf[j]);
      unsigned short h = f2bf(kf[j]);
      kha[j] = (short)h;
      kla[j] = (short)f2bf(kf[j] - bf2f(h));
    }
#pragma unroll
    for (int f = 0; f < 16; ++f) {
      const size_t soff = (size_t)(f * 16 + col) * 128 + off;
      bf16x8 bh = *(const bf16x8*)(Sh + soff);
      bf16x8 bl = *(const bf16x8*)(Sl + soff);
      accq[f] = __builtin_amdgcn_mfma_f32_16x16x32_bf16(qa,  bh, accq[f], 0, 0, 0);
      acck[f] = __builtin_amdgcn_mfma_f32_16x16x32_bf16(kha, bh, acck[f], 0, 0, 0);
      acck[f] = __builtin_amdgcn_mfma_f32_16x16x32_bf16(kla, bh, acck[f], 0, 0, 0);
      acck[f] = __builtin_amdgcn_mfma_f32_16x16x32_bf16(kha, bl, acck[f], 0, 0, 0);
    }
  }

  // epilogue: est partials + borderline worklist
  float part[4] = {0.f, 0.f, 0.f, 0.f};
#pragma unroll
  for (int f = 0; f < 16; ++f) {
    const int m = f * 16 + col;
#pragma unroll
    for (int r = 0; r < 4; ++r) {
      const float kp = acck[f][r];
      const float s = (kp > 0.f) ? 1.f : ((kp < 0.f) ? -1.f : 0.f);
      part[r] += s * accq[f][r];
      if (__builtin_fabsf(kp) < DELTA) {
        const int row = rowbase + kg * 4 + r;
        const unsigned int code = (kp > 0.f) ? 1u : ((kp < 0.f) ? 2u : 0u);
        const unsigned int idx = atomicAdd(wl_count, 1u);
        if (idx < wl_cap) wl[idx] = (code << 25) | ((unsigned int)row << 8) | (unsigned int)m;
      }
    }
  }
  // reduce over the 16 lanes sharing the same rows (xor low-4 lane bits)
#pragma unroll
  for (int r = 0; r < 4; ++r) {
    float v = part[r];
    v += __shfl_xor(v, 1);
    v += __shfl_xor(v, 2);
    v += __shfl_xor(v, 4);
    v += __shfl_xor(v, 8);
    if (col == 0) out[rowbase + kg * 4 + r] = v * DEQUANT;
  }
}

__global__ __launch_bounds__(256) void qjl_fix(
    const float* __restrict__ Q, const float* __restrict__ K, const float* __restrict__ S,
    float* __restrict__ out, const unsigned int* __restrict__ wl_count,
    const unsigned int* __restrict__ wl, unsigned int wl_cap) {
  unsigned int n = *wl_count;
  if (n > wl_cap) n = wl_cap;
  const int lane = threadIdx.x & 63;
  const unsigned int wid = blockIdx.x * (blockDim.x >> 6) + (threadIdx.x >> 6);
  const unsigned int nw = gridDim.x * (blockDim.x >> 6);
  for (unsigned int e = wid; e < n; e += nw) {
    const unsigned int ent = wl[e];
    const unsigned int m = ent & 255u;
    const unsigned int row = (ent >> 8) & 0x1FFFFu;
    const unsigned int code = ent >> 25;
    const float s_old = (code == 1u) ? 1.f : ((code == 2u) ? -1.f : 0.f);
    const float* kr = K + (size_t)row * 128;
    const float* qr = Q + (size_t)row * 128;
    const float* sr = S + (size_t)m * 128;
    const int d = lane * 2;
    double kp = (double)kr[d] * (double)sr[d] + (double)kr[d + 1] * (double)sr[d + 1];
    double qp = (double)qr[d] * (double)sr[d] + (double)qr[d + 1] * (double)sr[d + 1];
#pragma unroll
    for (int mask = 1; mask < 64; mask <<= 1) {
      kp += __shfl_xor(kp, mask);
      qp += __shfl_xor(qp, mask);
    }
    if (lane == 0) {
      const float s_new = (kp > 0.0) ? 1.f : ((kp < 0.0) ? -1.f : 0.f);
      const float dlt = (s_new - s_old) * (float)qp * DEQUANT;
      if (dlt != 0.f) atomicAdd(out + row, dlt);
    }
  }
}

extern "C" void kernel_launch(void* const* d_in, const int* in_sizes, int n_in,
                              void* d_out, int out_size, void* d_ws, size_t ws_size,
                              hipStream_t stream) {
  const float* Q = (const float*)d_in[0];
  const float* K = (const float*)d_in[1];
  const float* S = (const float*)d_in[2];
  float* out = (float*)d_out;
  const int rows = in_sizes[0] / 128;  // 4*32768 = 131072
  const int sn = in_sizes[2];          // 256*128 = 32768

  // workspace layout: [Sh bf16 sn][Sl bf16 sn][pad][counter u32][pad][worklist u32...]
  unsigned short* Sh = (unsigned short*)d_ws;
  unsigned short* Sl = Sh + sn;
  unsigned int* wl_count = (unsigned int*)((char*)d_ws + (size_t)sn * 4);
  unsigned int* wl = (unsigned int*)((char*)d_ws + (size_t)sn * 4 + 1024);
  unsigned int wl_cap = 0;
  const size_t used = (size_t)sn * 4 + 1024 + 16;
  if (ws_size > used) {
    size_t c = (ws_size - used) / 4;
    wl_cap = (c > 8000000) ? 8000000u : (unsigned int)c;
  }

  hipLaunchKernelGGL(qjl_prep, dim3((sn + 255) / 256), dim3(256), 0, stream,
                     S, Sh, Sl, wl_count, sn);
  hipLaunchKernelGGL(qjl_main, dim3(rows / 64), dim3(256), 0, stream,
                     Q, K, Sh, Sl, out, wl_count, wl, wl_cap);
  hipLaunchKernelGGL(qjl_fix, dim3(256), dim3(256), 0, stream,
                     Q, K, S, out, wl_count, wl, wl_cap);
}

// Round 2
// 412.091 us; speedup vs baseline: 1.0973x; 1.0973x over previous
//
#include <hip/hip_runtime.h>
#include <stdint.h>

// QJL estimator: est[row] = DEQ * sum_m sign(key_row . S_m) * (query_row . S_m)
//   kernel qjl_prep : split S (fp32) into Sh + Sl bf16 pair, zero worklist counter
//   kernel qjl_main : per-wave 16 rows x 256 m, m sliced by 64 to keep acc small.
//                     kproj = kh*Sh + kl*Sh + kh*Sl ; qproj = qh*Sh
//                     |kproj| < DELTA -> worklist
//   kernel qjl_fix  : fp64 recompute of borderline dots, atomic correction.
//
// MFMA layout (validated empirically in R1 on gfx950 mfma_f32_16x16x32_bf16):
//   both operands: lane l holds X[idx = l&15][k = (l>>4)*8 + j], j=0..7
//   D: arg0's idx -> D-row = (l>>4)*4 + r ; arg1's idx -> D-col = l&15
// Here arg0 = S-frag (idx = m within tile), arg1 = row-data frag (idx = row).

typedef __attribute__((ext_vector_type(8))) short bf16x8;
typedef __attribute__((ext_vector_type(4))) float f32x4;

#define DEQUANT 0.004895758348888673f  // sqrt(pi/2)/256
#define DELTA 0.01f

static __device__ __forceinline__ unsigned short f2bf(float f) {
  union { float f; uint32_t u; } v; v.f = f;
  return (unsigned short)((v.u + 0x7FFFu + ((v.u >> 16) & 1u)) >> 16);  // RNE
}
static __device__ __forceinline__ float bf2f(unsigned short h) {
  union { uint32_t u; float f; } v; v.u = ((uint32_t)h) << 16;
  return v.f;
}

__global__ void qjl_prep(const float* __restrict__ S, unsigned short* __restrict__ Sh,
                         unsigned short* __restrict__ Sl, unsigned int* __restrict__ wl_count,
                         int n) {
  int i = blockIdx.x * blockDim.x + threadIdx.x;
  if (i == 0) *wl_count = 0u;  // ws re-poisoned 0xAA before every call
  if (i < n) {
    float s = S[i];
    unsigned short h = f2bf(s);
    Sh[i] = h;
    Sl[i] = f2bf(s - bf2f(h));
  }
}

__global__ __launch_bounds__(256, 3) void qjl_main(
    const float* __restrict__ Q, const float* __restrict__ K,
    const unsigned short* __restrict__ Sh, const unsigned short* __restrict__ Sl,
    float* __restrict__ out, unsigned int* __restrict__ wl_count,
    unsigned int* __restrict__ wl, unsigned int wl_cap) {
  const int wave = threadIdx.x >> 6;
  const int lane = threadIdx.x & 63;
  const int col  = lane & 15;   // data-row within 16-row tile (D col)
  const int kg   = lane >> 4;   // k-group for operand frags
  const int rowbase = (blockIdx.x * 4 + wave) * 16;

  // ---- load 16 rows of Q and K once; hold bf16 B-frags in registers ----
  bf16x8 qB[4], khB[4], klB[4];
  const float* qrow = Q + (size_t)(rowbase + col) * 128 + kg * 8;
  const float* krow = K + (size_t)(rowbase + col) * 128 + kg * 8;
#pragma unroll
  for (int c = 0; c < 4; ++c) {
    float qf[8], kf[8];
    *(float4*)(&qf[0]) = *(const float4*)(qrow + c * 32);
    *(float4*)(&qf[4]) = *(const float4*)(qrow + c * 32 + 4);
    *(float4*)(&kf[0]) = *(const float4*)(krow + c * 32);
    *(float4*)(&kf[4]) = *(const float4*)(krow + c * 32 + 4);
#pragma unroll
    for (int j = 0; j < 8; ++j) {
      qB[c][j] = (short)f2bf(qf[j]);
      unsigned short h = f2bf(kf[j]);
      khB[c][j] = (short)h;
      klB[c][j] = (short)f2bf(kf[j] - bf2f(h));
    }
  }

  float part = 0.f;

  // ---- m sliced by 64: acc regs stay small (32 VGPR), reused per slice ----
#pragma unroll
  for (int s = 0; s < 4; ++s) {
    f32x4 accq[4], acck[4];
#pragma unroll
    for (int t = 0; t < 4; ++t) {
      accq[t] = (f32x4){0.f, 0.f, 0.f, 0.f};
      acck[t] = (f32x4){0.f, 0.f, 0.f, 0.f};
    }
#pragma unroll
    for (int t = 0; t < 4; ++t) {
      const unsigned short* shp = Sh + (size_t)(s * 64 + t * 16 + col) * 128 + kg * 8;
      const unsigned short* slp = Sl + (size_t)(s * 64 + t * 16 + col) * 128 + kg * 8;
#pragma unroll
      for (int c = 0; c < 4; ++c) {
        bf16x8 bh = *(const bf16x8*)(shp + c * 32);
        bf16x8 bl = *(const bf16x8*)(slp + c * 32);
        accq[t] = __builtin_amdgcn_mfma_f32_16x16x32_bf16(bh, qB[c],  accq[t], 0, 0, 0);
        acck[t] = __builtin_amdgcn_mfma_f32_16x16x32_bf16(bh, khB[c], acck[t], 0, 0, 0);
        acck[t] = __builtin_amdgcn_mfma_f32_16x16x32_bf16(bh, klB[c], acck[t], 0, 0, 0);
        acck[t] = __builtin_amdgcn_mfma_f32_16x16x32_bf16(bl, khB[c], acck[t], 0, 0, 0);
      }
    }
    // slice epilogue: sign * qproj, plus borderline worklist
#pragma unroll
    for (int t = 0; t < 4; ++t) {
#pragma unroll
      for (int r = 0; r < 4; ++r) {
        const float kp = acck[t][r];
        const float sg = (kp > 0.f) ? 1.f : ((kp < 0.f) ? -1.f : 0.f);
        part += sg * accq[t][r];
        if (__builtin_fabsf(kp) < DELTA) {
          const int m = s * 64 + t * 16 + kg * 4 + r;
          const int row = rowbase + col;
          const unsigned int code = (kp > 0.f) ? 1u : ((kp < 0.f) ? 2u : 0u);
          const unsigned int idx = atomicAdd(wl_count, 1u);
          if (idx < wl_cap) wl[idx] = (code << 25) | ((unsigned int)row << 8) | (unsigned int)m;
        }
      }
    }
  }

  // reduce the 4 k-groups holding the same data-row (xor lane bits 4,5)
  part += __shfl_xor(part, 16);
  part += __shfl_xor(part, 32);
  if (lane < 16) out[rowbase + lane] = part * DEQUANT;
}

__global__ __launch_bounds__(256) void qjl_fix(
    const float* __restrict__ Q, const float* __restrict__ K, const float* __restrict__ S,
    float* __restrict__ out, const unsigned int* __restrict__ wl_count,
    const unsigned int* __restrict__ wl, unsigned int wl_cap) {
  unsigned int n = *wl_count;
  if (n > wl_cap) n = wl_cap;
  const int lane = threadIdx.x & 63;
  const unsigned int wid = blockIdx.x * (blockDim.x >> 6) + (threadIdx.x >> 6);
  const unsigned int nw = gridDim.x * (blockDim.x >> 6);
  for (unsigned int e = wid; e < n; e += nw) {
    const unsigned int ent = wl[e];
    const unsigned int m = ent & 255u;
    const unsigned int row = (ent >> 8) & 0x1FFFFu;
    const unsigned int code = ent >> 25;
    const float s_old = (code == 1u) ? 1.f : ((code == 2u) ? -1.f : 0.f);
    const float* kr = K + (size_t)row * 128;
    const float* qr = Q + (size_t)row * 128;
    const float* sr = S + (size_t)m * 128;
    const int d = lane * 2;
    double kp = (double)kr[d] * (double)sr[d] + (double)kr[d + 1] * (double)sr[d + 1];
    double qp = (double)qr[d] * (double)sr[d] + (double)qr[d + 1] * (double)sr[d + 1];
#pragma unroll
    for (int mask = 1; mask < 64; mask <<= 1) {
      kp += __shfl_xor(kp, mask);
      qp += __shfl_xor(qp, mask);
    }
    if (lane == 0) {
      const float s_new = (kp > 0.0) ? 1.f : ((kp < 0.0) ? -1.f : 0.f);
      const float dlt = (s_new - s_old) * (float)qp * DEQUANT;
      if (dlt != 0.f) atomicAdd(out + row, dlt);
    }
  }
}

extern "C" void kernel_launch(void* const* d_in, const int* in_sizes, int n_in,
                              void* d_out, int out_size, void* d_ws, size_t ws_size,
                              hipStream_t stream) {
  const float* Q = (const float*)d_in[0];
  const float* K = (const float*)d_in[1];
  const float* S = (const float*)d_in[2];
  float* out = (float*)d_out;
  const int rows = in_sizes[0] / 128;  // 4*32768 = 131072
  const int sn = in_sizes[2];          // 256*128 = 32768

  // workspace: [Sh bf16 sn][Sl bf16 sn][pad][counter u32][pad][worklist u32...]
  unsigned short* Sh = (unsigned short*)d_ws;
  unsigned short* Sl = Sh + sn;
  unsigned int* wl_count = (unsigned int*)((char*)d_ws + (size_t)sn * 4);
  unsigned int* wl = (unsigned int*)((char*)d_ws + (size_t)sn * 4 + 1024);
  unsigned int wl_cap = 0;
  const size_t used = (size_t)sn * 4 + 1024 + 16;
  if (ws_size > used) {
    size_t c = (ws_size - used) / 4;
    wl_cap = (c > 8000000) ? 8000000u : (unsigned int)c;
  }

  hipLaunchKernelGGL(qjl_prep, dim3((sn + 255) / 256), dim3(256), 0, stream,
                     S, Sh, Sl, wl_count, sn);
  hipLaunchKernelGGL(qjl_main, dim3(rows / 64), dim3(256), 0, stream,
                     Q, K, Sh, Sl, out, wl_count, wl, wl_cap);
  hipLaunchKernelGGL(qjl_fix, dim3(1024), dim3(256), 0, stream,
                     Q, K, S, out, wl_count, wl, wl_cap);
}

// Round 3
// 280.323 us; speedup vs baseline: 1.6132x; 1.4701x over previous
//
#include <hip/hip_runtime.h>
#include <stdint.h>

// QJL estimator: est[row] = DEQ * sum_m sign(key_row . S_m) * (query_row . S_m)
//   qjl_prep : split S (fp32) into Sh + Sl bf16 pair
//   qjl_main : per-wave 16 rows x 256 m, m sliced by 64 (small acc, reused).
//              kproj = kh*Sh + kl*Sh + kh*Sl ; qproj = qh*Sh
//              |kproj| < DELTA -> per-BLOCK worklist (LDS atomics only; the R2
//              version's single global atomic counter serialized the whole GPU)
//   qjl_fix  : per-block segments, fp64 recompute of borderline dots, atomic fix.
//
// MFMA layout (validated empirically in R1/R2 on gfx950 mfma_f32_16x16x32_bf16):
//   both operands: lane l holds X[idx = l&15][k = (l>>4)*8 + j], j=0..7
//   D: arg0's idx -> D-row = (l>>4)*4 + r ; arg1's idx -> D-col = l&15

typedef __attribute__((ext_vector_type(8))) short bf16x8;
typedef __attribute__((ext_vector_type(4))) float f32x4;

#define DEQUANT 0.004895758348888673f  // sqrt(pi/2)/256
#define DELTA 0.01f
#define SEG 256  // worklist capacity per block

static __device__ __forceinline__ unsigned short f2bf(float f) {
  union { float f; uint32_t u; } v; v.f = f;
  return (unsigned short)((v.u + 0x7FFFu + ((v.u >> 16) & 1u)) >> 16);  // RNE
}
static __device__ __forceinline__ float bf2f(unsigned short h) {
  union { uint32_t u; float f; } v; v.u = ((uint32_t)h) << 16;
  return v.f;
}

__global__ void qjl_prep(const float* __restrict__ S, unsigned short* __restrict__ Sh,
                         unsigned short* __restrict__ Sl, int n) {
  int i = blockIdx.x * blockDim.x + threadIdx.x;
  if (i < n) {
    float s = S[i];
    unsigned short h = f2bf(s);
    Sh[i] = h;
    Sl[i] = f2bf(s - bf2f(h));
  }
}

__global__ __launch_bounds__(256, 4) void qjl_main(
    const float* __restrict__ Q, const float* __restrict__ K,
    const unsigned short* __restrict__ Sh, const unsigned short* __restrict__ Sl,
    float* __restrict__ out, unsigned int* __restrict__ blockCount,
    unsigned int* __restrict__ wl, unsigned int cap) {
  __shared__ unsigned int l_cnt;
  __shared__ unsigned int l_ent[SEG];

  const int wave = threadIdx.x >> 6;
  const int lane = threadIdx.x & 63;
  const int col  = lane & 15;   // data-row within 16-row tile (D col)
  const int kg   = lane >> 4;   // k-group for operand frags
  const int rowbase = (blockIdx.x * 4 + wave) * 16;

  if (threadIdx.x == 0) l_cnt = 0u;
  __syncthreads();

  // ---- load 16 rows of Q and K once; hold bf16 frags in registers ----
  bf16x8 qB[4], khB[4], klB[4];
  const float* qrow = Q + (size_t)(rowbase + col) * 128 + kg * 8;
  const float* krow = K + (size_t)(rowbase + col) * 128 + kg * 8;
#pragma unroll
  for (int c = 0; c < 4; ++c) {
    float qf[8], kf[8];
    *(float4*)(&qf[0]) = *(const float4*)(qrow + c * 32);
    *(float4*)(&qf[4]) = *(const float4*)(qrow + c * 32 + 4);
    *(float4*)(&kf[0]) = *(const float4*)(krow + c * 32);
    *(float4*)(&kf[4]) = *(const float4*)(krow + c * 32 + 4);
#pragma unroll
    for (int j = 0; j < 8; ++j) {
      qB[c][j] = (short)f2bf(qf[j]);
      unsigned short h = f2bf(kf[j]);
      khB[c][j] = (short)h;
      klB[c][j] = (short)f2bf(kf[j] - bf2f(h));
    }
  }

  float part = 0.f;

  // ---- m sliced by 64: acc regs stay small, reused per slice ----
#pragma unroll
  for (int s = 0; s < 4; ++s) {
    f32x4 accq[4], acck[4];
#pragma unroll
    for (int t = 0; t < 4; ++t) {
      accq[t] = (f32x4){0.f, 0.f, 0.f, 0.f};
      acck[t] = (f32x4){0.f, 0.f, 0.f, 0.f};
    }
#pragma unroll
    for (int t = 0; t < 4; ++t) {
      const unsigned short* shp = Sh + (size_t)(s * 64 + t * 16 + col) * 128 + kg * 8;
      const unsigned short* slp = Sl + (size_t)(s * 64 + t * 16 + col) * 128 + kg * 8;
#pragma unroll
      for (int c = 0; c < 4; ++c) {
        bf16x8 bh = *(const bf16x8*)(shp + c * 32);
        bf16x8 bl = *(const bf16x8*)(slp + c * 32);
        accq[t] = __builtin_amdgcn_mfma_f32_16x16x32_bf16(bh, qB[c],  accq[t], 0, 0, 0);
        acck[t] = __builtin_amdgcn_mfma_f32_16x16x32_bf16(bh, khB[c], acck[t], 0, 0, 0);
        acck[t] = __builtin_amdgcn_mfma_f32_16x16x32_bf16(bh, klB[c], acck[t], 0, 0, 0);
        acck[t] = __builtin_amdgcn_mfma_f32_16x16x32_bf16(bl, khB[c], acck[t], 0, 0, 0);
      }
    }
    // slice epilogue: sign * qproj, plus borderline worklist (LDS only)
#pragma unroll
    for (int t = 0; t < 4; ++t) {
#pragma unroll
      for (int r = 0; r < 4; ++r) {
        const float kp = acck[t][r];
        const float sg = (kp > 0.f) ? 1.f : ((kp < 0.f) ? -1.f : 0.f);
        part += sg * accq[t][r];
        if (__builtin_fabsf(kp) < DELTA) {
          const int m = s * 64 + t * 16 + kg * 4 + r;
          const int row = rowbase + col;
          const unsigned int code = (kp > 0.f) ? 1u : ((kp < 0.f) ? 2u : 0u);
          const unsigned int idx = atomicAdd(&l_cnt, 1u);
          if (idx < SEG) l_ent[idx] = (code << 25) | ((unsigned int)row << 8) | (unsigned int)m;
        }
      }
    }
  }

  // reduce the 4 k-groups holding the same data-row (xor lane bits 4,5)
  part += __shfl_xor(part, 16);
  part += __shfl_xor(part, 32);
  if (lane < 16) out[rowbase + lane] = part * DEQUANT;

  // flush per-block worklist segment
  __syncthreads();
  unsigned int n = l_cnt;
  if (n > cap) n = cap;
  if (threadIdx.x == 0) blockCount[blockIdx.x] = n;
  for (unsigned int i = threadIdx.x; i < n; i += 256)
    wl[(size_t)blockIdx.x * SEG + i] = l_ent[i];
}

__global__ __launch_bounds__(256) void qjl_fix(
    const float* __restrict__ Q, const float* __restrict__ K, const float* __restrict__ S,
    float* __restrict__ out, const unsigned int* __restrict__ blockCount,
    const unsigned int* __restrict__ wl) {
  const unsigned int n = blockCount[blockIdx.x];
  const int lane = threadIdx.x & 63;
  const int wave = threadIdx.x >> 6;
  for (unsigned int e = wave; e < n; e += 4) {
    const unsigned int ent = wl[(size_t)blockIdx.x * SEG + e];
    const unsigned int m = ent & 255u;
    const unsigned int row = (ent >> 8) & 0x1FFFFu;
    const unsigned int code = ent >> 25;
    const float s_old = (code == 1u) ? 1.f : ((code == 2u) ? -1.f : 0.f);
    const float* kr = K + (size_t)row * 128;
    const float* qr = Q + (size_t)row * 128;
    const float* sr = S + (size_t)m * 128;
    const int d = lane * 2;
    double kp = (double)kr[d] * (double)sr[d] + (double)kr[d + 1] * (double)sr[d + 1];
    double qp = (double)qr[d] * (double)sr[d] + (double)qr[d + 1] * (double)sr[d + 1];
#pragma unroll
    for (int mask = 1; mask < 64; mask <<= 1) {
      kp += __shfl_xor(kp, mask);
      qp += __shfl_xor(qp, mask);
    }
    if (lane == 0) {
      const float s_new = (kp > 0.0) ? 1.f : ((kp < 0.0) ? -1.f : 0.f);
      const float dlt = (s_new - s_old) * (float)qp * DEQUANT;
      if (dlt != 0.f) atomicAdd(out + row, dlt);
    }
  }
}

extern "C" void kernel_launch(void* const* d_in, const int* in_sizes, int n_in,
                              void* d_out, int out_size, void* d_ws, size_t ws_size,
                              hipStream_t stream) {
  const float* Q = (const float*)d_in[0];
  const float* K = (const float*)d_in[1];
  const float* S = (const float*)d_in[2];
  float* out = (float*)d_out;
  const int rows = in_sizes[0] / 128;  // 4*32768 = 131072
  const int sn = in_sizes[2];          // 256*128 = 32768
  const int nblk = rows / 64;          // 2048

  // workspace: [Sh bf16 sn][Sl bf16 sn][blockCount u32 nblk][wl u32 nblk*SEG]
  unsigned short* Sh = (unsigned short*)d_ws;
  unsigned short* Sl = Sh + sn;
  unsigned int* blockCount = (unsigned int*)((char*)d_ws + (size_t)sn * 4);
  unsigned int* wl = blockCount + nblk;
  unsigned int cap = SEG;
  const size_t need = (size_t)sn * 4 + (size_t)nblk * 4 + (size_t)nblk * SEG * 4;
  if (ws_size < need) {
    size_t avail = (ws_size > (size_t)sn * 4 + (size_t)nblk * 4)
                       ? (ws_size - (size_t)sn * 4 - (size_t)nblk * 4) / ((size_t)nblk * 4)
                       : 0;
    cap = (unsigned int)((avail < SEG) ? avail : SEG);
  }

  hipLaunchKernelGGL(qjl_prep, dim3((sn + 255) / 256), dim3(256), 0, stream,
                     S, Sh, Sl, sn);
  hipLaunchKernelGGL(qjl_main, dim3(nblk), dim3(256), 0, stream,
                     Q, K, Sh, Sl, out, blockCount, wl, cap);
  hipLaunchKernelGGL(qjl_fix, dim3(nblk), dim3(256), 0, stream,
                     Q, K, S, out, blockCount, wl);
}

// Round 4
// 219.166 us; speedup vs baseline: 2.0633x; 1.2790x over previous
//
#include <hip/hip_runtime.h>
#include <stdint.h>

// QJL estimator: est[row] = DEQ * sum_m sign(key_row . S_m) * (query_row . S_m)
//   qjl_prep : emit S as bf16 hi/lo pair in MFMA *fragment order*:
//              ST[s][h][t][c][lane][j]  (s=m-slice/64, h=hi|lo, t=m-tile/16,
//              c=k-chunk/32, lane=kg*16+mt, j=k within 8)
//              -> every S-frag load in qjl_main is base + lane*16B, one
//              coalesced 1KB instruction, 32KB/slice working set (= L1 size).
//   qjl_main : per-wave 32 rows (two 16-row tiles) x 256 m, m sliced by 64.
//              kproj = kh*Sh + kl*Sh + kh*Sl ; qproj = qh*Sh
//              |kproj| < DELTA -> per-block worklist (LDS atomics only)
//   qjl_fix  : per-block segments, fp64 recompute of borderline dots, atomic fix.
//
// MFMA layout (validated empirically R1-R3, gfx950 mfma_f32_16x16x32_bf16):
//   operands: lane l holds X[idx = l&15][k = (l>>4)*8 + j], j=0..7
//   D: arg0's idx -> D-row = (l>>4)*4 + r ; arg1's idx -> D-col = l&15

typedef __attribute__((ext_vector_type(8))) short bf16x8;
typedef __attribute__((ext_vector_type(4))) float f32x4;

#define DEQUANT 0.004895758348888673f  // sqrt(pi/2)/256
#define DELTA 0.01f
#define SEG 512  // worklist capacity per block (expected ~23/block)

static __device__ __forceinline__ unsigned short f2bf(float f) {
  union { float f; uint32_t u; } v; v.f = f;
  return (unsigned short)((v.u + 0x7FFFu + ((v.u >> 16) & 1u)) >> 16);  // RNE
}
static __device__ __forceinline__ float bf2f(unsigned short h) {
  union { uint32_t u; float f; } v; v.u = ((uint32_t)h) << 16;
  return v.f;
}

// ST element count = 4(s) * 2(h) * 4(t) * 4(c) * 64(lane) * 8(j) = 65536 shorts
__global__ void qjl_prep(const float* __restrict__ S, unsigned short* __restrict__ ST) {
  int i = blockIdx.x * blockDim.x + threadIdx.x;  // grid covers 65536
  const int j = i & 7;
  const int l = (i >> 3) & 63;
  const int c = (i >> 9) & 3;
  const int t = (i >> 11) & 3;
  const int h = (i >> 13) & 1;
  const int s = i >> 14;
  const int m = s * 64 + t * 16 + (l & 15);
  const int k = c * 32 + (l >> 4) * 8 + j;
  const float f = S[m * 128 + k];
  const unsigned short hi = f2bf(f);
  ST[i] = h ? f2bf(f - bf2f(hi)) : hi;
}

__global__ __launch_bounds__(256, 2) void qjl_main(
    const float* __restrict__ Q, const float* __restrict__ K,
    const unsigned short* __restrict__ ST,
    float* __restrict__ out, unsigned int* __restrict__ blockCount,
    unsigned int* __restrict__ wl) {
  __shared__ unsigned int l_cnt;
  __shared__ unsigned int l_ent[SEG];

  const int wave = threadIdx.x >> 6;
  const int lane = threadIdx.x & 63;
  const int col  = lane & 15;   // data-row within 16-row tile (D col)
  const int kg   = lane >> 4;   // k-group for operand frags
  const int rowbase = (blockIdx.x * 4 + wave) * 32;  // 32 rows per wave

  if (threadIdx.x == 0) l_cnt = 0u;
  __syncthreads();

  // ---- load 2x16 rows of Q and K once; hold bf16 frags in registers ----
  bf16x8 qB[2][4], khB[2][4], klB[2][4];
#pragma unroll
  for (int a = 0; a < 2; ++a) {
    const float* qrow = Q + (size_t)(rowbase + a * 16 + col) * 128 + kg * 8;
    const float* krow = K + (size_t)(rowbase + a * 16 + col) * 128 + kg * 8;
#pragma unroll
    for (int c = 0; c < 4; ++c) {
      float qf[8], kf[8];
      *(float4*)(&qf[0]) = *(const float4*)(qrow + c * 32);
      *(float4*)(&qf[4]) = *(const float4*)(qrow + c * 32 + 4);
      *(float4*)(&kf[0]) = *(const float4*)(krow + c * 32);
      *(float4*)(&kf[4]) = *(const float4*)(krow + c * 32 + 4);
#pragma unroll
      for (int j = 0; j < 8; ++j) {
        qB[a][c][j] = (short)f2bf(qf[j]);
        unsigned short h = f2bf(kf[j]);
        khB[a][c][j] = (short)h;
        klB[a][c][j] = (short)f2bf(kf[j] - bf2f(h));
      }
    }
  }

  float part[2] = {0.f, 0.f};

  // ---- m sliced by 64: acc regs reused per slice ----
#pragma unroll
  for (int s = 0; s < 4; ++s) {
    f32x4 accq[2][4], acck[2][4];
#pragma unroll
    for (int a = 0; a < 2; ++a)
#pragma unroll
      for (int t = 0; t < 4; ++t) {
        accq[a][t] = (f32x4){0.f, 0.f, 0.f, 0.f};
        acck[a][t] = (f32x4){0.f, 0.f, 0.f, 0.f};
      }
#pragma unroll
    for (int t = 0; t < 4; ++t) {
#pragma unroll
      for (int c = 0; c < 4; ++c) {
        // frag id f = ((s*2+h)*4 + t)*4 + c ; short offset = f*512 + lane*8
        const bf16x8 bh = *(const bf16x8*)(ST + (size_t)(((s * 2 + 0) * 4 + t) * 4 + c) * 512 + lane * 8);
        const bf16x8 bl = *(const bf16x8*)(ST + (size_t)(((s * 2 + 1) * 4 + t) * 4 + c) * 512 + lane * 8);
#pragma unroll
        for (int a = 0; a < 2; ++a) {
          accq[a][t] = __builtin_amdgcn_mfma_f32_16x16x32_bf16(bh, qB[a][c],  accq[a][t], 0, 0, 0);
          acck[a][t] = __builtin_amdgcn_mfma_f32_16x16x32_bf16(bh, khB[a][c], acck[a][t], 0, 0, 0);
          acck[a][t] = __builtin_amdgcn_mfma_f32_16x16x32_bf16(bh, klB[a][c], acck[a][t], 0, 0, 0);
          acck[a][t] = __builtin_amdgcn_mfma_f32_16x16x32_bf16(bl, khB[a][c], acck[a][t], 0, 0, 0);
        }
      }
    }
    // slice epilogue: sign * qproj, plus borderline worklist (LDS only)
#pragma unroll
    for (int a = 0; a < 2; ++a)
#pragma unroll
      for (int t = 0; t < 4; ++t)
#pragma unroll
        for (int r = 0; r < 4; ++r) {
          const float kp = acck[a][t][r];
          const float sg = (kp > 0.f) ? 1.f : ((kp < 0.f) ? -1.f : 0.f);
          part[a] += sg * accq[a][t][r];
          if (__builtin_fabsf(kp) < DELTA) {
            const int m = s * 64 + t * 16 + kg * 4 + r;
            const int row = rowbase + a * 16 + col;
            const unsigned int code = (kp > 0.f) ? 1u : ((kp < 0.f) ? 2u : 0u);
            const unsigned int idx = atomicAdd(&l_cnt, 1u);
            if (idx < SEG) l_ent[idx] = (code << 25) | ((unsigned int)row << 8) | (unsigned int)m;
          }
        }
  }

  // reduce the 4 k-groups holding the same data-row (xor lane bits 4,5)
#pragma unroll
  for (int a = 0; a < 2; ++a) {
    float v = part[a];
    v += __shfl_xor(v, 16);
    v += __shfl_xor(v, 32);
    if (lane < 16) out[rowbase + a * 16 + lane] = v * DEQUANT;
  }

  // flush per-block worklist segment
  __syncthreads();
  unsigned int n = l_cnt;
  if (n > SEG) n = SEG;
  if (threadIdx.x == 0) blockCount[blockIdx.x] = n;
  for (unsigned int i = threadIdx.x; i < n; i += 256)
    wl[(size_t)blockIdx.x * SEG + i] = l_ent[i];
}

__global__ __launch_bounds__(256) void qjl_fix(
    const float* __restrict__ Q, const float* __restrict__ K, const float* __restrict__ S,
    float* __restrict__ out, const unsigned int* __restrict__ blockCount,
    const unsigned int* __restrict__ wl) {
  const unsigned int n = blockCount[blockIdx.x];
  const int lane = threadIdx.x & 63;
  const int wave = threadIdx.x >> 6;
  for (unsigned int e = wave; e < n; e += 4) {
    const unsigned int ent = wl[(size_t)blockIdx.x * SEG + e];
    const unsigned int m = ent & 255u;
    const unsigned int row = (ent >> 8) & 0x1FFFFu;
    const unsigned int code = ent >> 25;
    const float s_old = (code == 1u) ? 1.f : ((code == 2u) ? -1.f : 0.f);
    const float* kr = K + (size_t)row * 128;
    const float* qr = Q + (size_t)row * 128;
    const float* sr = S + (size_t)m * 128;
    const int d = lane * 2;
    double kp = (double)kr[d] * (double)sr[d] + (double)kr[d + 1] * (double)sr[d + 1];
    double qp = (double)qr[d] * (double)sr[d] + (double)qr[d + 1] * (double)sr[d + 1];
#pragma unroll
    for (int mask = 1; mask < 64; mask <<= 1) {
      kp += __shfl_xor(kp, mask);
      qp += __shfl_xor(qp, mask);
    }
    if (lane == 0) {
      const float s_new = (kp > 0.0) ? 1.f : ((kp < 0.0) ? -1.f : 0.f);
      const float dlt = (s_new - s_old) * (float)qp * DEQUANT;
      if (dlt != 0.f) atomicAdd(out + row, dlt);
    }
  }
}

extern "C" void kernel_launch(void* const* d_in, const int* in_sizes, int n_in,
                              void* d_out, int out_size, void* d_ws, size_t ws_size,
                              hipStream_t stream) {
  const float* Q = (const float*)d_in[0];
  const float* K = (const float*)d_in[1];
  const float* S = (const float*)d_in[2];
  float* out = (float*)d_out;
  const int rows = in_sizes[0] / 128;  // 4*32768 = 131072
  const int sn = in_sizes[2];          // 256*128 = 32768
  const int nblk = rows / 128;         // 1024 blocks, 128 rows each

  // workspace: [ST bf16 2*sn][blockCount u32 nblk][wl u32 nblk*SEG]
  unsigned short* ST = (unsigned short*)d_ws;
  unsigned int* blockCount = (unsigned int*)((char*)d_ws + (size_t)sn * 4);
  unsigned int* wl = blockCount + nblk;

  hipLaunchKernelGGL(qjl_prep, dim3((2 * sn) / 256), dim3(256), 0, stream, S, ST);
  hipLaunchKernelGGL(qjl_main, dim3(nblk), dim3(256), 0, stream,
                     Q, K, ST, out, blockCount, wl);
  hipLaunchKernelGGL(qjl_fix, dim3(nblk), dim3(256), 0, stream,
                     Q, K, S, out, blockCount, wl);
}